// Round 5
// baseline (834.057 us; speedup 1.0000x reference)
//
#include <hip/hip_runtime.h>
#include <hip/hip_bf16.h>

#define N_NODES 20000
#define NE      400000

typedef _Float16 half8  __attribute__((ext_vector_type(8)));
typedef _Float16 half2v __attribute__((ext_vector_type(2)));
typedef float    floatx4 __attribute__((ext_vector_type(4)));

// ---------------------------------------------------------------------------
// CSR build: count -> scan (2 blocks, one per edge set) -> scatter
// ---------------------------------------------------------------------------
__global__ void count_kernel(const int* __restrict__ dst0, int* cnt0,
                             const int* __restrict__ dst1, int* cnt1) {
    int e = blockIdx.x * blockDim.x + threadIdx.x;
    if (e < NE) {
        atomicAdd(&cnt0[dst0[e]], 1);
        atomicAdd(&cnt1[dst1[e]], 1);
    }
}

__global__ __launch_bounds__(256) void scan2_kernel(
    const int* __restrict__ cnt0, int* offs0, int* cur0, float* dinv0,
    const int* __restrict__ cnt1, int* offs1, int* cur1, float* dinv1, int n)
{
    const int*  cnt    = blockIdx.x ? cnt1  : cnt0;
    int*        offs   = blockIdx.x ? offs1 : offs0;
    int*        cursor = blockIdx.x ? cur1  : cur0;
    float*      dinv   = blockIdx.x ? dinv1 : dinv0;

    __shared__ int wsum[4];
    __shared__ int carry;
    int t = threadIdx.x, lane = t & 63, w = t >> 6;
    if (t == 0) carry = 0;
    __syncthreads();
    for (int base = 0; base < n; base += 256) {
        int i = base + t;
        int v = (i < n) ? cnt[i] : 0;
        int s = v;
        #pragma unroll
        for (int off = 1; off < 64; off <<= 1) {
            int x = __shfl_up(s, off);
            if (lane >= off) s += x;
        }
        if (lane == 63) wsum[w] = s;
        __syncthreads();
        int add = carry;
        for (int q = 0; q < w; ++q) add += wsum[q];
        if (i < n) {
            int excl = add + s - v;
            offs[i] = excl;
            cursor[i] = excl;
            dinv[i] = rsqrtf(1.0f + (float)v);
        }
        __syncthreads();
        if (t == 0) carry += wsum[0] + wsum[1] + wsum[2] + wsum[3];
        __syncthreads();
    }
    if (t == 0) offs[n] = carry;
}

__global__ void scatter_kernel(const int* __restrict__ dst0, int* cur0, int* eid0,
                               const int* __restrict__ dst1, int* cur1, int* eid1) {
    int e = blockIdx.x * blockDim.x + threadIdx.x;
    if (e < NE) {
        int p0 = atomicAdd(&cur0[dst0[e]], 1); eid0[p0] = e;
        int p1 = atomicAdd(&cur1[dst1[e]], 1); eid1[p1] = e;
    }
}

// ---------------------------------------------------------------------------
// All weight->B-fragment conversions in ONE launch (144 blocks):
//  [0,32): p0W2 (8,256)  [32,64): p1W2 (8,256)
//  [64,96): g0W (16,128) [96,128): g1W (16,128)  [128,144): c3W (8,128)
// Bf[((nt*KST+ks)*64+lane)*8+j] = W[ks*32+(lane>>4)*8+j][nt*16+(lane&15)]
// ---------------------------------------------------------------------------
__global__ __launch_bounds__(256) void wfrag_all_kernel(
    const float* __restrict__ W2a, const float* __restrict__ W2b,
    const float* __restrict__ gWa, const float* __restrict__ gWb,
    const float* __restrict__ c3W,
    _Float16* __restrict__ o_w2a, _Float16* __restrict__ o_w2b,
    _Float16* __restrict__ o_gwa, _Float16* __restrict__ o_gwb,
    _Float16* __restrict__ o_c3)
{
    int b = blockIdx.x;
    const float* W; _Float16* O; int KST, NC, b0;
    if      (b < 32)  { W = W2a; O = o_w2a; KST = 8;  NC = 256; b0 = 0;   }
    else if (b < 64)  { W = W2b; O = o_w2b; KST = 8;  NC = 256; b0 = 32;  }
    else if (b < 96)  { W = gWa; O = o_gwa; KST = 16; NC = 128; b0 = 64;  }
    else if (b < 128) { W = gWb; O = o_gwb; KST = 16; NC = 128; b0 = 96;  }
    else              { W = c3W; O = o_c3;  KST = 8;  NC = 128; b0 = 128; }

    int tid = (b - b0) * 256 + threadIdx.x;
    int l  = tid & 63;
    int ks = (tid >> 6) % KST;
    int nt = tid / (64 * KST);
    int n  = nt * 16 + (l & 15);
    int kb = ks * 32 + (l >> 4) * 8;
    half8 v;
    #pragma unroll
    for (int j = 0; j < 8; ++j) v[j] = (_Float16)W[(kb + j) * NC + n];
    *(half8*)&O[(size_t)tid * 8] = v;
}

// ---------------------------------------------------------------------------
// PointNet, both layers in one launch (grid 2500 x 2). Block = 256 thr,
// owns 8 nodes, 64-edge chunks, double-buffered edge metadata.
// Phase 1: packed-fp16 VALU hidden = relu(ef@W1+b1) -> A-frags in LDS.
// Phase 2: f16 MFMA vs global B-frags. Epilogue: sorted-lid fast-path
// segmented max into LDS. Output h fp16 row-major [N,512].
// ---------------------------------------------------------------------------
__global__ __launch_bounds__(256, 3) void pointnet_fused_kernel(
    const float* __restrict__ pos0, const float* __restrict__ pos1,
    const int* __restrict__ ei0, const int* __restrict__ ei1,
    const int* __restrict__ eid0, const int* __restrict__ eid1,
    const int* __restrict__ offs0, const int* __restrict__ offs1,
    const float* __restrict__ W1a, const float* __restrict__ W1b,
    const float* __restrict__ b1a, const float* __restrict__ b1b,
    const _Float16* __restrict__ Bf0, const _Float16* __restrict__ Bf1,
    const float* __restrict__ b2a, const float* __restrict__ b2b,
    _Float16* __restrict__ out)
{
    const int L = blockIdx.y;
    const float* pos = L ? pos1 : pos0;
    const int* src = L ? ei1 : ei0;
    const int* dst = (L ? ei1 : ei0) + NE;
    const int* eid = L ? eid1 : eid0;
    const int* offs = L ? offs1 : offs0;
    const float* W1 = L ? W1b : W1a;
    const float* b1 = L ? b1b : b1a;
    const _Float16* Bf = L ? Bf1 : Bf0;
    const float* b2 = L ? b2b : b2a;
    const int co = L * 256;

    __shared__ float s_ef[2][6][64];
    __shared__ int   s_lid[2][64];
    __shared__ _Float16 s_w1h[6][256];
    __shared__ _Float16 s_b1h[256];
    __shared__ float s_b2[256];
    __shared__ _Float16 s_afr[4 * 8 * 64 * 8];   // 32 KB, A-frag layout
    __shared__ unsigned int sacc[8][256];        // 8 KB

    const int t = threadIdx.x;
    const int nb = blockIdx.x * 8;
    const int lane = t & 63;
    const int wv = t >> 6;

    #pragma unroll
    for (int j = 0; j < 6; ++j) s_w1h[j][t] = (_Float16)W1[j * 256 + t];
    s_b1h[t] = (_Float16)b1[t];
    s_b2[t] = b2[t];
    #pragma unroll
    for (int ln = 0; ln < 8; ++ln) sacc[ln][t] = 0u;

    const int estart = offs[nb];
    const int eend   = offs[nb + 8];

    // preload first chunk metadata into buffer 0
    if (t < 64) {
        int slot = estart + t;
        int lid = -1;
        float f[6] = {0.f, 0.f, 0.f, 0.f, 0.f, 0.f};
        if (slot < eend) {
            int ed = eid[slot];
            int s = src[ed], d = dst[ed];
            lid = d - nb;
            float sx = pos[s * 3 + 0], sy = pos[s * 3 + 1], sz = pos[s * 3 + 2];
            float dx = pos[d * 3 + 0], dy = pos[d * 3 + 1], dz = pos[d * 3 + 2];
            f[0] = sx; f[1] = sy; f[2] = sz;
            f[3] = sx - dx; f[4] = sy - dy; f[5] = sz - dz;
        }
        s_lid[0][t] = lid;
        #pragma unroll
        for (int j = 0; j < 6; ++j) s_ef[0][j][t] = f[j];
    }
    __syncthreads();

    const int mt_e = lane >> 4, m_e = lane & 15;
    const int kb = wv * 64;
    const int rbase = (lane >> 4) * 4;
    const half8 z8 = (half8)(_Float16)0.f;

    int cur = 0;
    for (int ebase = estart; ebase < eend; ebase += 64) {
        // ---- phase 1: hidden (packed fp16) -> A-frags ----
        {
            _Float16 efh[6];
            #pragma unroll
            for (int j = 0; j < 6; ++j) efh[j] = (_Float16)s_ef[cur][j][lane];
            #pragma unroll
            for (int c4 = 0; c4 < 4; ++c4) {
                int k0 = kb + c4 * 16;
                half8 alo = *(const half8*)&s_b1h[k0];
                half8 ahi = *(const half8*)&s_b1h[k0 + 8];
                #pragma unroll
                for (int j = 0; j < 6; ++j) {
                    half8 wlo = *(const half8*)&s_w1h[j][k0];
                    half8 whi = *(const half8*)&s_w1h[j][k0 + 8];
                    half8 es = (half8)efh[j];
                    alo += wlo * es;
                    ahi += whi * es;
                }
                alo = __builtin_elementwise_max(alo, z8);
                ahi = __builtin_elementwise_max(ahi, z8);
                int ks = k0 >> 5;
                int q0 = (k0 >> 3) & 3;
                int base = (mt_e * 8 + ks) * 64 + m_e;
                *(half8*)&s_afr[(base + 16 * q0) * 8]       = alo;
                *(half8*)&s_afr[(base + 16 * (q0 + 1)) * 8] = ahi;
            }
        }
        __syncthreads();

        // ---- prefetch next chunk metadata (overlaps phase 2) ----
        int nxt = cur ^ 1;
        if (t < 64 && ebase + 64 < eend) {
            int slot = ebase + 64 + t;
            int lid = -1;
            float f[6] = {0.f, 0.f, 0.f, 0.f, 0.f, 0.f};
            if (slot < eend) {
                int ed = eid[slot];
                int s = src[ed], d = dst[ed];
                lid = d - nb;
                float sx = pos[s * 3 + 0], sy = pos[s * 3 + 1], sz = pos[s * 3 + 2];
                float dx = pos[d * 3 + 0], dy = pos[d * 3 + 1], dz = pos[d * 3 + 2];
                f[0] = sx; f[1] = sy; f[2] = sz;
                f[3] = sx - dx; f[4] = sy - dy; f[5] = sz - dz;
            }
            s_lid[nxt][t] = lid;
            #pragma unroll
            for (int j = 0; j < 6; ++j) s_ef[nxt][j][t] = f[j];
        }

        // ---- phase 2: MFMA (64 edges x 64 ch per wave) ----
        floatx4 acc[4][4];
        #pragma unroll
        for (int mt = 0; mt < 4; ++mt)
            #pragma unroll
            for (int q = 0; q < 4; ++q) acc[mt][q] = (floatx4){0.f, 0.f, 0.f, 0.f};

        #pragma unroll
        for (int ks = 0; ks < 8; ++ks) {
            half8 a[4];
            #pragma unroll
            for (int mt = 0; mt < 4; ++mt)
                a[mt] = *(const half8*)&s_afr[((mt * 8 + ks) * 64 + lane) * 8];
            #pragma unroll
            for (int q = 0; q < 4; ++q) {
                int nt = wv * 4 + q;
                half8 b = *(const half8*)&Bf[(size_t)((nt * 8 + ks) * 64 + lane) * 8];
                #pragma unroll
                for (int mt = 0; mt < 4; ++mt)
                    acc[mt][q] = __builtin_amdgcn_mfma_f32_16x16x32_f16(a[mt], b, acc[mt][q], 0, 0, 0);
            }
        }

        // ---- epilogue: segmented max, sorted-lid fast path ----
        #pragma unroll
        for (int mt = 0; mt < 4; ++mt) {
            int4 l4 = *(const int4*)&s_lid[cur][mt * 16 + rbase];
            #pragma unroll
            for (int q = 0; q < 4; ++q) {
                int ch = (wv * 4 + q) * 16 + (lane & 15);
                float bb = s_b2[ch];
                float v0 = acc[mt][q][0] + bb;
                float v1 = acc[mt][q][1] + bb;
                float v2 = acc[mt][q][2] + bb;
                float v3 = acc[mt][q][3] + bb;
                if (l4.x == l4.w) {
                    float m = fmaxf(fmaxf(v0, v1), fmaxf(v2, v3));
                    if (l4.x >= 0 && m > 0.f) atomicMax(&sacc[l4.x][ch], __float_as_uint(m));
                } else {
                    if (l4.x >= 0 && v0 > 0.f) atomicMax(&sacc[l4.x][ch], __float_as_uint(v0));
                    if (l4.y >= 0 && v1 > 0.f) atomicMax(&sacc[l4.y][ch], __float_as_uint(v1));
                    if (l4.z >= 0 && v2 > 0.f) atomicMax(&sacc[l4.z][ch], __float_as_uint(v2));
                    if (l4.w >= 0 && v3 > 0.f) atomicMax(&sacc[l4.w][ch], __float_as_uint(v3));
                }
            }
        }
        __syncthreads();
        cur = nxt;
    }

    // ---- final store (fp16 row-major) ----
    #pragma unroll
    for (int ln = 0; ln < 8; ++ln)
        out[(size_t)(nb + ln) * 512 + co + t] = (_Float16)__uint_as_float(sacc[ln][t]);
}

// ---------------------------------------------------------------------------
// MFMA GEMM (pair-fused via grid.z): C[M,128] = opt_relu(A@Bf + bias)
// block 256 = 4 waves; tile 32 rows x 64 cols; grid (M/32, 2, nsets).
// ---------------------------------------------------------------------------
template <int KSTEPS, int RELU>
__global__ __launch_bounds__(256) void gemm_mfma2_kernel(
    const _Float16* __restrict__ A,
    const _Float16* __restrict__ Bfa, const _Float16* __restrict__ Bfb,
    const float* __restrict__ bias,
    float* __restrict__ Ca, float* __restrict__ Cb)
{
    const _Float16* Bf = blockIdx.z ? Bfb : Bfa;
    float* C = blockIdx.z ? Cb : Ca;

    const int t = threadIdx.x;
    const int lane = t & 63;
    const int wv = t >> 6;
    const int mb = blockIdx.x * 32;
    const int nt = blockIdx.y * 4 + wv;
    const int K = KSTEPS * 32;

    const size_t arow0 = (size_t)(mb + (lane & 15)) * K + (lane >> 4) * 8;
    const size_t arow1 = arow0 + (size_t)16 * K;

    floatx4 acc0 = (floatx4){0.f, 0.f, 0.f, 0.f};
    floatx4 acc1 = (floatx4){0.f, 0.f, 0.f, 0.f};

    #pragma unroll
    for (int ks = 0; ks < KSTEPS; ++ks) {
        half8 a0 = *(const half8*)&A[arow0 + ks * 32];
        half8 a1 = *(const half8*)&A[arow1 + ks * 32];
        half8 b  = *(const half8*)&Bf[(size_t)((nt * KSTEPS + ks) * 64 + lane) * 8];
        acc0 = __builtin_amdgcn_mfma_f32_16x16x32_f16(a0, b, acc0, 0, 0, 0);
        acc1 = __builtin_amdgcn_mfma_f32_16x16x32_f16(a1, b, acc1, 0, 0, 0);
    }

    const int col = nt * 16 + (lane & 15);
    const int rb  = (lane >> 4) * 4;
    const float bb = bias ? bias[col] : 0.f;
    #pragma unroll
    for (int r = 0; r < 4; ++r) {
        float v0 = acc0[r] + bb;
        float v1 = acc1[r] + bb;
        if (RELU) { v0 = fmaxf(v0, 0.f); v1 = fmaxf(v1, 0.f); }
        C[(size_t)(mb + rb + r) * 128 + col]      = v0;
        C[(size_t)(mb + 16 + rb + r) * 128 + col] = v1;
    }
}

// ---------------------------------------------------------------------------
// GCN gather (pair-fused via grid.y), wave-per-node, no atomics.
// Writes h2 as fp16 [N,256].
// ---------------------------------------------------------------------------
__global__ __launch_bounds__(256) void gcn_gather2_kernel(
    const int* __restrict__ ei0, const int* __restrict__ ei1,
    const int* __restrict__ eid0, const int* __restrict__ eid1,
    const int* __restrict__ offs0, const int* __restrict__ offs1,
    const float* __restrict__ dinv0, const float* __restrict__ dinv1,
    const float* __restrict__ xw0, const float* __restrict__ xw1,
    const float* __restrict__ b0, const float* __restrict__ b1,
    _Float16* __restrict__ h2)
{
    const int L = blockIdx.y;
    const int* src = L ? ei1 : ei0;
    const int* eid = L ? eid1 : eid0;
    const int* offs = L ? offs1 : offs0;
    const float* dinv = L ? dinv1 : dinv0;
    const float* xw = L ? xw1 : xw0;
    const float* b = L ? b1 : b0;
    const int co = L * 128;

    const int t = threadIdx.x;
    const int lane = t & 63;
    const int i = blockIdx.x * 4 + (t >> 6);
    const int e0 = offs[i], e1 = offs[i + 1];
    const float di = dinv[i];

    float ax = 0.f, ay = 0.f;
    for (int base = e0; base < e1; base += 64) {
        int k = base + lane;
        int s = 0; float nr = 0.f;
        if (k < e1) {
            int e = eid[k];
            s = src[e];
            nr = dinv[s];
        }
        int m = min(64, e1 - base);
        for (int j = 0; j < m; ++j) {
            int   sj = __shfl(s, j);
            float nj = __shfl(nr, j);
            float2 v = *(const float2*)&xw[(size_t)sj * 128 + 2 * lane];
            ax += v.x * nj;
            ay += v.y * nj;
        }
    }

    float2 xi = *(const float2*)&xw[(size_t)i * 128 + 2 * lane];
    float vx = ax * di + xi.x * di * di + b[2 * lane];
    float vy = ay * di + xi.y * di * di + b[2 * lane + 1];
    half2v o;
    o[0] = (_Float16)fmaxf(vx, 0.f);
    o[1] = (_Float16)fmaxf(vy, 0.f);
    *(half2v*)&h2[(size_t)i * 256 + co + 2 * lane] = o;
}

// ---------------------------------------------------------------------------
// Final classifier: out[3] = z_flat @ cls_W + cls_b  (out pre-zeroed)
// ---------------------------------------------------------------------------
__global__ __launch_bounds__(256) void classifier_kernel(
    const float* __restrict__ z, const float* __restrict__ clsW,
    const float* __restrict__ clsb, float* __restrict__ out)
{
    float a0 = 0.f, a1 = 0.f, a2 = 0.f;
    const int total = N_NODES * 128;
    for (int i = blockIdx.x * blockDim.x + threadIdx.x; i < total;
         i += gridDim.x * blockDim.x) {
        float v = z[i];
        a0 += v * clsW[(size_t)i * 3 + 0];
        a1 += v * clsW[(size_t)i * 3 + 1];
        a2 += v * clsW[(size_t)i * 3 + 2];
    }
    #pragma unroll
    for (int off = 32; off > 0; off >>= 1) {
        a0 += __shfl_down(a0, off);
        a1 += __shfl_down(a1, off);
        a2 += __shfl_down(a2, off);
    }
    __shared__ float sred[12];
    int w = threadIdx.x >> 6;
    if ((threadIdx.x & 63) == 0) { sred[w * 3] = a0; sred[w * 3 + 1] = a1; sred[w * 3 + 2] = a2; }
    __syncthreads();
    if (threadIdx.x == 0) {
        float r0 = 0.f, r1 = 0.f, r2 = 0.f;
        #pragma unroll
        for (int q = 0; q < 4; ++q) { r0 += sred[q * 3]; r1 += sred[q * 3 + 1]; r2 += sred[q * 3 + 2]; }
        atomicAdd(&out[0], r0); atomicAdd(&out[1], r1); atomicAdd(&out[2], r2);
    }
    if (blockIdx.x == 0 && threadIdx.x < 3) atomicAdd(&out[threadIdx.x], clsb[threadIdx.x]);
}

// ---------------------------------------------------------------------------
extern "C" void kernel_launch(void* const* d_in, const int* in_sizes, int n_in,
                              void* d_out, int out_size, void* d_ws, size_t ws_size,
                              hipStream_t stream) {
    const float* pos0 = (const float*)d_in[0];
    const float* pos1 = (const float*)d_in[1];
    const int*   ei0  = (const int*)d_in[2];
    const int*   ei1  = (const int*)d_in[3];
    const float* p0W1 = (const float*)d_in[6];
    const float* p0b1 = (const float*)d_in[7];
    const float* p0W2 = (const float*)d_in[8];
    const float* p0b2 = (const float*)d_in[9];
    const float* p1W1 = (const float*)d_in[10];
    const float* p1b1 = (const float*)d_in[11];
    const float* p1W2 = (const float*)d_in[12];
    const float* p1b2 = (const float*)d_in[13];
    const float* g0W  = (const float*)d_in[14];
    const float* g0b  = (const float*)d_in[15];
    const float* g1W  = (const float*)d_in[16];
    const float* g1b  = (const float*)d_in[17];
    const float* c3W  = (const float*)d_in[18];
    const float* c3b  = (const float*)d_in[19];
    const float* clsW = (const float*)d_in[20];
    const float* clsb = (const float*)d_in[21];

    const int* d0 = ei0 + NE;
    const int* d1 = ei1 + NE;

    float* ws = (float*)d_ws;
    _Float16* h   = (_Float16*)ws;               // [N,512] fp16
    float* xw0    = ws + 5120000;                // [N,128] fp32
    float* xw1    = ws + 7680000;
    _Float16* h2  = (_Float16*)(ws + 10240000);  // [N,256] fp16
    float* z      = ws + 12800000;               // [N,128] fp32
    int*   cnt0  = (int*)(ws + 15360000);        // [N]
    int*   cnt1  = (int*)(ws + 15380000);
    int*   cur0  = (int*)(ws + 15400000);
    int*   cur1  = (int*)(ws + 15420000);
    int*   offs0 = (int*)(ws + 15440000);        // [N+1]
    int*   offs1 = (int*)(ws + 15460004);        // [N+1]
    int*   eid0  = (int*)(ws + 15480008);        // [E]
    int*   eid1  = (int*)(ws + 15880008);
    float* dinv0 = ws + 16280008;                // [N]
    float* dinv1 = ws + 16300008;
    _Float16* w2f0 = (_Float16*)(ws + 16320008); // 65536 halfs
    _Float16* w2f1 = (_Float16*)(ws + 16352776);
    _Float16* gwf0 = (_Float16*)(ws + 16385544); // 65536 halfs
    _Float16* gwf1 = (_Float16*)(ws + 16418312);
    _Float16* c3f  = (_Float16*)(ws + 16451080); // 32768 halfs

    hipMemsetAsync(cnt0, 0, (size_t)2 * N_NODES * sizeof(int), stream);
    hipMemsetAsync(d_out, 0, 3 * sizeof(float), stream);

    // CSR build (by dst) + all weight fragment conversions
    count_kernel<<<(NE + 255) / 256, 256, 0, stream>>>(d0, cnt0, d1, cnt1);
    wfrag_all_kernel<<<144, 256, 0, stream>>>(p0W2, p1W2, g0W, g1W, c3W,
                                              w2f0, w2f1, gwf0, gwf1, c3f);
    scan2_kernel<<<2, 256, 0, stream>>>(cnt0, offs0, cur0, dinv0,
                                        cnt1, offs1, cur1, dinv1, N_NODES);
    scatter_kernel<<<(NE + 255) / 256, 256, 0, stream>>>(d0, cur0, eid0, d1, cur1, eid1);

    // PointNet, both layers in one dispatch -> h [N,512] fp16
    pointnet_fused_kernel<<<dim3(N_NODES / 8, 2), 256, 0, stream>>>(
        pos0, pos1, ei0, ei1, eid0, eid1, offs0, offs1,
        p0W1, p1W1, p0b1, p1b1, w2f0, w2f1, p0b2, p1b2, h);

    // xw pair = h @ gW (fp16 MFMA, K=512) -> fp32
    gemm_mfma2_kernel<16, 0><<<dim3(N_NODES / 32, 2, 2), 256, 0, stream>>>(
        h, gwf0, gwf1, nullptr, xw0, xw1);

    // fused GCN aggregation pair -> h2 [N,256] fp16
    gcn_gather2_kernel<<<dim3(N_NODES / 4, 2), 256, 0, stream>>>(
        ei0, ei1, eid0, eid1, offs0, offs1, dinv0, dinv1, xw0, xw1, g0b, g1b, h2);

    // z = relu(h2 @ c3W + c3b) (fp16 MFMA, K=256) -> fp32
    gemm_mfma2_kernel<8, 1><<<dim3(N_NODES / 32, 2, 1), 256, 0, stream>>>(
        h2, c3f, c3f, c3b, z, z);

    // out = z_flat @ clsW + clsb
    classifier_kernel<<<2048, 256, 0, stream>>>(z, clsW, clsb, (float*)d_out);
}

// Round 6
// 660.467 us; speedup vs baseline: 1.2628x; 1.2628x over previous
//
#include <hip/hip_runtime.h>
#include <hip/hip_bf16.h>

#define N_NODES 20000
#define NE      400000

typedef _Float16 half8  __attribute__((ext_vector_type(8)));
typedef _Float16 half2v __attribute__((ext_vector_type(2)));
typedef float    floatx4 __attribute__((ext_vector_type(4)));

// ---------------------------------------------------------------------------
// CSR build: count -> scan (2 blocks, one per edge set) -> scatter
// ---------------------------------------------------------------------------
__global__ void count_kernel(const int* __restrict__ dst0, int* cnt0,
                             const int* __restrict__ dst1, int* cnt1) {
    int e = blockIdx.x * blockDim.x + threadIdx.x;
    if (e < NE) {
        atomicAdd(&cnt0[dst0[e]], 1);
        atomicAdd(&cnt1[dst1[e]], 1);
    }
}

__global__ __launch_bounds__(256) void scan2_kernel(
    const int* __restrict__ cnt0, int* offs0, int* cur0, float* dinv0,
    const int* __restrict__ cnt1, int* offs1, int* cur1, float* dinv1, int n)
{
    const int*  cnt    = blockIdx.x ? cnt1  : cnt0;
    int*        offs   = blockIdx.x ? offs1 : offs0;
    int*        cursor = blockIdx.x ? cur1  : cur0;
    float*      dinv   = blockIdx.x ? dinv1 : dinv0;

    __shared__ int wsum[4];
    __shared__ int carry;
    int t = threadIdx.x, lane = t & 63, w = t >> 6;
    if (t == 0) carry = 0;
    __syncthreads();
    for (int base = 0; base < n; base += 256) {
        int i = base + t;
        int v = (i < n) ? cnt[i] : 0;
        int s = v;
        #pragma unroll
        for (int off = 1; off < 64; off <<= 1) {
            int x = __shfl_up(s, off);
            if (lane >= off) s += x;
        }
        if (lane == 63) wsum[w] = s;
        __syncthreads();
        int add = carry;
        for (int q = 0; q < w; ++q) add += wsum[q];
        if (i < n) {
            int excl = add + s - v;
            offs[i] = excl;
            cursor[i] = excl;
            dinv[i] = rsqrtf(1.0f + (float)v);
        }
        __syncthreads();
        if (t == 0) carry += wsum[0] + wsum[1] + wsum[2] + wsum[3];
        __syncthreads();
    }
    if (t == 0) offs[n] = carry;
}

__global__ void scatter_kernel(const int* __restrict__ dst0, int* cur0, int* eid0,
                               const int* __restrict__ dst1, int* cur1, int* eid1) {
    int e = blockIdx.x * blockDim.x + threadIdx.x;
    if (e < NE) {
        int p0 = atomicAdd(&cur0[dst0[e]], 1); eid0[p0] = e;
        int p1 = atomicAdd(&cur1[dst1[e]], 1); eid1[p1] = e;
    }
}

// ---------------------------------------------------------------------------
// All weight->B-fragment conversions in ONE launch (144 blocks).
// Bf[((nt*KST+ks)*64+lane)*8+j] = W[ks*32+(lane>>4)*8+j][nt*16+(lane&15)]
// ---------------------------------------------------------------------------
__global__ __launch_bounds__(256) void wfrag_all_kernel(
    const float* __restrict__ W2a, const float* __restrict__ W2b,
    const float* __restrict__ gWa, const float* __restrict__ gWb,
    const float* __restrict__ c3W,
    _Float16* __restrict__ o_w2a, _Float16* __restrict__ o_w2b,
    _Float16* __restrict__ o_gwa, _Float16* __restrict__ o_gwb,
    _Float16* __restrict__ o_c3)
{
    int b = blockIdx.x;
    const float* W; _Float16* O; int KST, NC, b0;
    if      (b < 32)  { W = W2a; O = o_w2a; KST = 8;  NC = 256; b0 = 0;   }
    else if (b < 64)  { W = W2b; O = o_w2b; KST = 8;  NC = 256; b0 = 32;  }
    else if (b < 96)  { W = gWa; O = o_gwa; KST = 16; NC = 128; b0 = 64;  }
    else if (b < 128) { W = gWb; O = o_gwb; KST = 16; NC = 128; b0 = 96;  }
    else              { W = c3W; O = o_c3;  KST = 8;  NC = 128; b0 = 128; }

    int tid = (b - b0) * 256 + threadIdx.x;
    int l  = tid & 63;
    int ks = (tid >> 6) % KST;
    int nt = tid / (64 * KST);
    int n  = nt * 16 + (l & 15);
    int kb = ks * 32 + (l >> 4) * 8;
    half8 v;
    #pragma unroll
    for (int j = 0; j < 8; ++j) v[j] = (_Float16)W[(kb + j) * NC + n];
    *(half8*)&O[(size_t)tid * 8] = v;
}

// ---------------------------------------------------------------------------
// PointNet, both layers in one launch (grid 2500 x 2). Block = 256 thr,
// owns 8 nodes, 32-edge chunks (acc[2][4] keeps regs small -- 64-edge
// chunks spilled to scratch in round 5: FETCH 16->779 MB), double-buffered
// edge metadata. Phase 1: packed-fp16 hidden -> A-frags in LDS.
// Phase 2: f16 MFMA vs global B-frags (L2-resident). Epilogue: sorted-lid
// fast-path segmented max in LDS. Output h fp16 row-major [N,512].
// ---------------------------------------------------------------------------
__global__ __launch_bounds__(256) void pointnet_fused_kernel(
    const float* __restrict__ pos0, const float* __restrict__ pos1,
    const int* __restrict__ ei0, const int* __restrict__ ei1,
    const int* __restrict__ eid0, const int* __restrict__ eid1,
    const int* __restrict__ offs0, const int* __restrict__ offs1,
    const float* __restrict__ W1a, const float* __restrict__ W1b,
    const float* __restrict__ b1a, const float* __restrict__ b1b,
    const _Float16* __restrict__ Bf0, const _Float16* __restrict__ Bf1,
    const float* __restrict__ b2a, const float* __restrict__ b2b,
    _Float16* __restrict__ out)
{
    const int L = blockIdx.y;
    const float* pos = L ? pos1 : pos0;
    const int* src = L ? ei1 : ei0;
    const int* dst = (L ? ei1 : ei0) + NE;
    const int* eid = L ? eid1 : eid0;
    const int* offs = L ? offs1 : offs0;
    const float* W1 = L ? W1b : W1a;
    const float* b1 = L ? b1b : b1a;
    const _Float16* Bf = L ? Bf1 : Bf0;
    const float* b2 = L ? b2b : b2a;
    const int co = L * 256;

    __shared__ float s_ef[2][6][32];
    __shared__ int   s_lid[2][32];
    __shared__ _Float16 s_w1h[6][256];
    __shared__ _Float16 s_b1h[256];
    __shared__ float s_b2[256];
    __shared__ _Float16 s_afr[2 * 8 * 64 * 8];   // 16 KB
    __shared__ unsigned int sacc[8][256];        // 8 KB

    const int t = threadIdx.x;
    const int nb = blockIdx.x * 8;
    const int lane = t & 63;
    const int wv = t >> 6;

    #pragma unroll
    for (int j = 0; j < 6; ++j) s_w1h[j][t] = (_Float16)W1[j * 256 + t];
    s_b1h[t] = (_Float16)b1[t];
    s_b2[t] = b2[t];
    #pragma unroll
    for (int ln = 0; ln < 8; ++ln) sacc[ln][t] = 0u;

    const int estart = offs[nb];
    const int eend   = offs[nb + 8];

    // preload first chunk metadata into buffer 0
    if (t < 32) {
        int slot = estart + t;
        int lid = -1;
        float f[6] = {0.f, 0.f, 0.f, 0.f, 0.f, 0.f};
        if (slot < eend) {
            int ed = eid[slot];
            int s = src[ed], d = dst[ed];
            lid = d - nb;
            float sx = pos[s * 3 + 0], sy = pos[s * 3 + 1], sz = pos[s * 3 + 2];
            float dx = pos[d * 3 + 0], dy = pos[d * 3 + 1], dz = pos[d * 3 + 2];
            f[0] = sx; f[1] = sy; f[2] = sz;
            f[3] = sx - dx; f[4] = sy - dy; f[5] = sz - dz;
        }
        s_lid[0][t] = lid;
        #pragma unroll
        for (int j = 0; j < 6; ++j) s_ef[0][j][t] = f[j];
    }
    __syncthreads();

    const int e    = t & 31;
    const int ksid = t >> 5;
    const int mt_e = e >> 4, m_e = e & 15;
    const int rbase = (lane >> 4) * 4;
    const half8 z8 = (half8)(_Float16)0.f;

    int cur = 0;
    for (int ebase = estart; ebase < eend; ebase += 32) {
        // ---- phase 1: hidden (packed fp16) -> A-frags; 32 ch per thread ----
        {
            _Float16 efh[6];
            #pragma unroll
            for (int j = 0; j < 6; ++j) efh[j] = (_Float16)s_ef[cur][j][e];
            #pragma unroll
            for (int q = 0; q < 4; ++q) {
                int k0 = ksid * 32 + q * 8;
                half8 a = *(const half8*)&s_b1h[k0];
                #pragma unroll
                for (int j = 0; j < 6; ++j)
                    a += (*(const half8*)&s_w1h[j][k0]) * (half8)efh[j];
                a = __builtin_elementwise_max(a, z8);
                *(half8*)&s_afr[((mt_e * 8 + ksid) * 64 + m_e + 16 * q) * 8] = a;
            }
        }
        __syncthreads();

        // ---- prefetch next chunk metadata (overlaps phase 2) ----
        int nxt = cur ^ 1;
        if (t < 32 && ebase + 32 < eend) {
            int slot = ebase + 32 + t;
            int lid = -1;
            float f[6] = {0.f, 0.f, 0.f, 0.f, 0.f, 0.f};
            if (slot < eend) {
                int ed = eid[slot];
                int s = src[ed], d = dst[ed];
                lid = d - nb;
                float sx = pos[s * 3 + 0], sy = pos[s * 3 + 1], sz = pos[s * 3 + 2];
                float dx = pos[d * 3 + 0], dy = pos[d * 3 + 1], dz = pos[d * 3 + 2];
                f[0] = sx; f[1] = sy; f[2] = sz;
                f[3] = sx - dx; f[4] = sy - dy; f[5] = sz - dz;
            }
            s_lid[nxt][t] = lid;
            #pragma unroll
            for (int j = 0; j < 6; ++j) s_ef[nxt][j][t] = f[j];
        }

        // ---- phase 2: MFMA (32 edges x 64 ch per wave) ----
        floatx4 acc[2][4];
        #pragma unroll
        for (int mt = 0; mt < 2; ++mt)
            #pragma unroll
            for (int q = 0; q < 4; ++q) acc[mt][q] = (floatx4){0.f, 0.f, 0.f, 0.f};

        #pragma unroll
        for (int ks = 0; ks < 8; ++ks) {
            half8 a0 = *(const half8*)&s_afr[((0 * 8 + ks) * 64 + lane) * 8];
            half8 a1 = *(const half8*)&s_afr[((1 * 8 + ks) * 64 + lane) * 8];
            #pragma unroll
            for (int q = 0; q < 4; ++q) {
                int nt = wv * 4 + q;
                half8 b = *(const half8*)&Bf[(size_t)((nt * 8 + ks) * 64 + lane) * 8];
                acc[0][q] = __builtin_amdgcn_mfma_f32_16x16x32_f16(a0, b, acc[0][q], 0, 0, 0);
                acc[1][q] = __builtin_amdgcn_mfma_f32_16x16x32_f16(a1, b, acc[1][q], 0, 0, 0);
            }
        }

        // ---- epilogue: segmented max, sorted-lid fast path ----
        #pragma unroll
        for (int mt = 0; mt < 2; ++mt) {
            int4 l4 = *(const int4*)&s_lid[cur][mt * 16 + rbase];
            #pragma unroll
            for (int q = 0; q < 4; ++q) {
                int ch = (wv * 4 + q) * 16 + (lane & 15);
                float bb = s_b2[ch];
                float v0 = acc[mt][q][0] + bb;
                float v1 = acc[mt][q][1] + bb;
                float v2 = acc[mt][q][2] + bb;
                float v3 = acc[mt][q][3] + bb;
                if (l4.x == l4.w) {
                    float m = fmaxf(fmaxf(v0, v1), fmaxf(v2, v3));
                    if (l4.x >= 0 && m > 0.f) atomicMax(&sacc[l4.x][ch], __float_as_uint(m));
                } else {
                    if (l4.x >= 0 && v0 > 0.f) atomicMax(&sacc[l4.x][ch], __float_as_uint(v0));
                    if (l4.y >= 0 && v1 > 0.f) atomicMax(&sacc[l4.y][ch], __float_as_uint(v1));
                    if (l4.z >= 0 && v2 > 0.f) atomicMax(&sacc[l4.z][ch], __float_as_uint(v2));
                    if (l4.w >= 0 && v3 > 0.f) atomicMax(&sacc[l4.w][ch], __float_as_uint(v3));
                }
            }
        }
        __syncthreads();
        cur = nxt;
    }

    // ---- final store (fp16 row-major) ----
    #pragma unroll
    for (int ln = 0; ln < 8; ++ln)
        out[(size_t)(nb + ln) * 512 + co + t] = (_Float16)__uint_as_float(sacc[ln][t]);
}

// ---------------------------------------------------------------------------
// MFMA GEMM (pair-fused via grid.z): C[M,128] = opt_relu(A@Bf + bias)
// block 256 = 4 waves; tile 32 rows x 64 cols; grid (M/32, 2, nsets).
// ---------------------------------------------------------------------------
template <int KSTEPS, int RELU, typename OutT>
__global__ __launch_bounds__(256) void gemm_mfma2_kernel(
    const _Float16* __restrict__ A,
    const _Float16* __restrict__ Bfa, const _Float16* __restrict__ Bfb,
    const float* __restrict__ bias,
    OutT* __restrict__ Ca, OutT* __restrict__ Cb)
{
    const _Float16* Bf = blockIdx.z ? Bfb : Bfa;
    OutT* C = blockIdx.z ? Cb : Ca;

    const int t = threadIdx.x;
    const int lane = t & 63;
    const int wv = t >> 6;
    const int mb = blockIdx.x * 32;
    const int nt = blockIdx.y * 4 + wv;
    const int K = KSTEPS * 32;

    const size_t arow0 = (size_t)(mb + (lane & 15)) * K + (lane >> 4) * 8;
    const size_t arow1 = arow0 + (size_t)16 * K;

    floatx4 acc0 = (floatx4){0.f, 0.f, 0.f, 0.f};
    floatx4 acc1 = (floatx4){0.f, 0.f, 0.f, 0.f};

    #pragma unroll
    for (int ks = 0; ks < KSTEPS; ++ks) {
        half8 a0 = *(const half8*)&A[arow0 + ks * 32];
        half8 a1 = *(const half8*)&A[arow1 + ks * 32];
        half8 b  = *(const half8*)&Bf[(size_t)((nt * KSTEPS + ks) * 64 + lane) * 8];
        acc0 = __builtin_amdgcn_mfma_f32_16x16x32_f16(a0, b, acc0, 0, 0, 0);
        acc1 = __builtin_amdgcn_mfma_f32_16x16x32_f16(a1, b, acc1, 0, 0, 0);
    }

    const int col = nt * 16 + (lane & 15);
    const int rb  = (lane >> 4) * 4;
    const float bb = bias ? bias[col] : 0.f;
    #pragma unroll
    for (int r = 0; r < 4; ++r) {
        float v0 = acc0[r] + bb;
        float v1 = acc1[r] + bb;
        if (RELU) { v0 = fmaxf(v0, 0.f); v1 = fmaxf(v1, 0.f); }
        C[(size_t)(mb + rb + r) * 128 + col]      = (OutT)v0;
        C[(size_t)(mb + 16 + rb + r) * 128 + col] = (OutT)v1;
    }
}

// ---------------------------------------------------------------------------
// GCN gather (pair-fused via grid.y), wave-per-node, no atomics.
// xw is fp16 (halves the dominant gather traffic); fp32 accumulation.
// Writes h2 as fp16 [N,256].
// ---------------------------------------------------------------------------
__global__ __launch_bounds__(256) void gcn_gather2_kernel(
    const int* __restrict__ ei0, const int* __restrict__ ei1,
    const int* __restrict__ eid0, const int* __restrict__ eid1,
    const int* __restrict__ offs0, const int* __restrict__ offs1,
    const float* __restrict__ dinv0, const float* __restrict__ dinv1,
    const _Float16* __restrict__ xw0, const _Float16* __restrict__ xw1,
    const float* __restrict__ b0, const float* __restrict__ b1,
    _Float16* __restrict__ h2)
{
    const int L = blockIdx.y;
    const int* src = L ? ei1 : ei0;
    const int* eid = L ? eid1 : eid0;
    const int* offs = L ? offs1 : offs0;
    const float* dinv = L ? dinv1 : dinv0;
    const _Float16* xw = L ? xw1 : xw0;
    const float* b = L ? b1 : b0;
    const int co = L * 128;

    const int t = threadIdx.x;
    const int lane = t & 63;
    const int i = blockIdx.x * 4 + (t >> 6);
    const int e0 = offs[i], e1 = offs[i + 1];
    const float di = dinv[i];

    float ax = 0.f, ay = 0.f;
    for (int base = e0; base < e1; base += 64) {
        int k = base + lane;
        int s = 0; float nr = 0.f;
        if (k < e1) {
            int e = eid[k];
            s = src[e];
            nr = dinv[s];
        }
        int m = min(64, e1 - base);
        for (int j = 0; j < m; ++j) {
            int   sj = __shfl(s, j);
            float nj = __shfl(nr, j);
            half2v v = *(const half2v*)&xw[(size_t)sj * 128 + 2 * lane];
            ax += (float)v[0] * nj;
            ay += (float)v[1] * nj;
        }
    }

    half2v xi = *(const half2v*)&xw[(size_t)i * 128 + 2 * lane];
    float vx = ax * di + (float)xi[0] * di * di + b[2 * lane];
    float vy = ay * di + (float)xi[1] * di * di + b[2 * lane + 1];
    half2v o;
    o[0] = (_Float16)fmaxf(vx, 0.f);
    o[1] = (_Float16)fmaxf(vy, 0.f);
    *(half2v*)&h2[(size_t)i * 256 + co + 2 * lane] = o;
}

// ---------------------------------------------------------------------------
// Final classifier: out[3] = z_flat @ cls_W + cls_b  (out pre-zeroed)
// ---------------------------------------------------------------------------
__global__ __launch_bounds__(256) void classifier_kernel(
    const float* __restrict__ z, const float* __restrict__ clsW,
    const float* __restrict__ clsb, float* __restrict__ out)
{
    float a0 = 0.f, a1 = 0.f, a2 = 0.f;
    const int total = N_NODES * 128;
    for (int i = blockIdx.x * blockDim.x + threadIdx.x; i < total;
         i += gridDim.x * blockDim.x) {
        float v = z[i];
        a0 += v * clsW[(size_t)i * 3 + 0];
        a1 += v * clsW[(size_t)i * 3 + 1];
        a2 += v * clsW[(size_t)i * 3 + 2];
    }
    #pragma unroll
    for (int off = 32; off > 0; off >>= 1) {
        a0 += __shfl_down(a0, off);
        a1 += __shfl_down(a1, off);
        a2 += __shfl_down(a2, off);
    }
    __shared__ float sred[12];
    int w = threadIdx.x >> 6;
    if ((threadIdx.x & 63) == 0) { sred[w * 3] = a0; sred[w * 3 + 1] = a1; sred[w * 3 + 2] = a2; }
    __syncthreads();
    if (threadIdx.x == 0) {
        float r0 = 0.f, r1 = 0.f, r2 = 0.f;
        #pragma unroll
        for (int q = 0; q < 4; ++q) { r0 += sred[q * 3]; r1 += sred[q * 3 + 1]; r2 += sred[q * 3 + 2]; }
        atomicAdd(&out[0], r0); atomicAdd(&out[1], r1); atomicAdd(&out[2], r2);
    }
    if (blockIdx.x == 0 && threadIdx.x < 3) atomicAdd(&out[threadIdx.x], clsb[threadIdx.x]);
}

// ---------------------------------------------------------------------------
extern "C" void kernel_launch(void* const* d_in, const int* in_sizes, int n_in,
                              void* d_out, int out_size, void* d_ws, size_t ws_size,
                              hipStream_t stream) {
    const float* pos0 = (const float*)d_in[0];
    const float* pos1 = (const float*)d_in[1];
    const int*   ei0  = (const int*)d_in[2];
    const int*   ei1  = (const int*)d_in[3];
    const float* p0W1 = (const float*)d_in[6];
    const float* p0b1 = (const float*)d_in[7];
    const float* p0W2 = (const float*)d_in[8];
    const float* p0b2 = (const float*)d_in[9];
    const float* p1W1 = (const float*)d_in[10];
    const float* p1b1 = (const float*)d_in[11];
    const float* p1W2 = (const float*)d_in[12];
    const float* p1b2 = (const float*)d_in[13];
    const float* g0W  = (const float*)d_in[14];
    const float* g0b  = (const float*)d_in[15];
    const float* g1W  = (const float*)d_in[16];
    const float* g1b  = (const float*)d_in[17];
    const float* c3W  = (const float*)d_in[18];
    const float* c3b  = (const float*)d_in[19];
    const float* clsW = (const float*)d_in[20];
    const float* clsb = (const float*)d_in[21];

    const int* d0 = ei0 + NE;
    const int* d1 = ei1 + NE;

    float* ws = (float*)d_ws;
    _Float16* h   = (_Float16*)ws;               // [N,512] fp16
    _Float16* xw0 = (_Float16*)(ws + 5120000);   // [N,128] fp16
    _Float16* xw1 = (_Float16*)(ws + 7680000);
    _Float16* h2  = (_Float16*)(ws + 10240000);  // [N,256] fp16
    float* z      = ws + 12800000;               // [N,128] fp32
    int*   cnt0  = (int*)(ws + 15360000);        // [N]
    int*   cnt1  = (int*)(ws + 15380000);
    int*   cur0  = (int*)(ws + 15400000);
    int*   cur1  = (int*)(ws + 15420000);
    int*   offs0 = (int*)(ws + 15440000);        // [N+1]
    int*   offs1 = (int*)(ws + 15460004);        // [N+1]
    int*   eid0  = (int*)(ws + 15480008);        // [E]
    int*   eid1  = (int*)(ws + 15880008);
    float* dinv0 = ws + 16280008;                // [N]
    float* dinv1 = ws + 16300008;
    _Float16* w2f0 = (_Float16*)(ws + 16320008); // 65536 halfs
    _Float16* w2f1 = (_Float16*)(ws + 16352776);
    _Float16* gwf0 = (_Float16*)(ws + 16385544); // 65536 halfs
    _Float16* gwf1 = (_Float16*)(ws + 16418312);
    _Float16* c3f  = (_Float16*)(ws + 16451080); // 32768 halfs

    hipMemsetAsync(cnt0, 0, (size_t)2 * N_NODES * sizeof(int), stream);
    hipMemsetAsync(d_out, 0, 3 * sizeof(float), stream);

    // CSR build (by dst) + all weight fragment conversions
    count_kernel<<<(NE + 255) / 256, 256, 0, stream>>>(d0, cnt0, d1, cnt1);
    wfrag_all_kernel<<<144, 256, 0, stream>>>(p0W2, p1W2, g0W, g1W, c3W,
                                              w2f0, w2f1, gwf0, gwf1, c3f);
    scan2_kernel<<<2, 256, 0, stream>>>(cnt0, offs0, cur0, dinv0,
                                        cnt1, offs1, cur1, dinv1, N_NODES);
    scatter_kernel<<<(NE + 255) / 256, 256, 0, stream>>>(d0, cur0, eid0, d1, cur1, eid1);

    // PointNet, both layers in one dispatch -> h [N,512] fp16
    pointnet_fused_kernel<<<dim3(N_NODES / 8, 2), 256, 0, stream>>>(
        pos0, pos1, ei0, ei1, eid0, eid1, offs0, offs1,
        p0W1, p1W1, p0b1, p1b1, w2f0, w2f1, p0b2, p1b2, h);

    // xw pair = h @ gW (fp16 MFMA, K=512) -> fp16
    gemm_mfma2_kernel<16, 0, _Float16><<<dim3(N_NODES / 32, 2, 2), 256, 0, stream>>>(
        h, gwf0, gwf1, nullptr, xw0, xw1);

    // fused GCN aggregation pair -> h2 [N,256] fp16
    gcn_gather2_kernel<<<dim3(N_NODES / 4, 2), 256, 0, stream>>>(
        ei0, ei1, eid0, eid1, offs0, offs1, dinv0, dinv1, xw0, xw1, g0b, g1b, h2);

    // z = relu(h2 @ c3W + c3b) (fp16 MFMA, K=256) -> fp32
    gemm_mfma2_kernel<8, 1, float><<<dim3(N_NODES / 32, 2, 1), 256, 0, stream>>>(
        h2, c3f, c3f, c3b, z, z);

    // out = z_flat @ clsW + clsb
    classifier_kernel<<<2048, 256, 0, stream>>>(z, clsW, clsb, (float*)d_out);
}